// Round 2
// 23936.684 us; speedup vs baseline: 1.2104x; 1.2104x over previous
//
#include <hip/hip_runtime.h>
#include <hip/hip_bf16.h>

// GRU backbone: B=64 S=2048 D=256 V=256 L=4
// Phases per call: cast weights->bf16, embed, then per layer {gi GEMM, scan}, final GEMM.
// Scan: 4 blocks x 512 thr, batch-tile 16, Wh bf16 register-resident (48 frags/wave),
// gate-triple column ownership per wave, h dbuf in LDS (A-frag order).
// gi GEMM writes scan-lane-major layout (48B contiguous per lane per step);
// scan loads gi straight to registers (3x dwordx4, reg double-buffer, 2x-unrolled loop);
// per-step __syncthreads (full vmcnt drain) replaced by lgkmcnt(0)-only raw s_barrier.
// This round: resubmit after infra failure; tail prefetch overread removed (uniform clamp).

#define B_ 64
#define S_ 2048
#define D_ 256
#define V_ 256
#define L_ 4

typedef short  s16x8 __attribute__((ext_vector_type(8)));
typedef float  f32x4 __attribute__((ext_vector_type(4)));

static __device__ __forceinline__ unsigned short f2b(float f){
  union { float f; unsigned int u; } v; v.f = f;
  unsigned int u = v.u;
  return (unsigned short)((u + 0x7FFFu + ((u >> 16) & 1u)) >> 16);  // RNE
}
static __device__ __forceinline__ float b2f(unsigned short s){
  union { unsigned int u; float f; } v; v.u = ((unsigned int)s) << 16; return v.f;
}

static __device__ __forceinline__ void lds_load16(void* lds, const void* g){
  __builtin_amdgcn_global_load_lds(
      (const __attribute__((address_space(1))) unsigned int*)g,
      (__attribute__((address_space(3))) unsigned int*)lds, 16, 0, 0);
}

__global__ void cast_bf16_kernel(const float* __restrict__ src,
                                 unsigned short* __restrict__ dst, int n){
  int i = blockIdx.x * 256 + threadIdx.x;
  if (i < n) dst[i] = f2b(src[i]);
}

__global__ void embed_kernel(const int* __restrict__ x, const float* __restrict__ emb,
                             unsigned short* __restrict__ seq){
  int bs = blockIdx.x;
  int d  = threadIdx.x;
  int tok = x[bs];
  seq[(size_t)bs * D_ + d] = f2b(emb[tok * D_ + d]);
}

// C[M,N] = A[M,K] * Bw[N,K]^T + bias ; A,Bw bf16 ; 128x128 tile, BK=32
// OUTF32=1: f32 row-major output (final logits GEMM).
// OUTF32=0: bf16 output in SCAN-LANE-MAJOR layout for gru_scan:
//   element (b, s, gate g, hidden d) -> ushort index
//   ((btile*2048+s)*512 + (d>>5)*64 + ((b&15)>>2)*16 + (d&15))*24 + (((d>>4)&1)*4 + (b&3))*3 + g
//   (each scan lane's 24 values contiguous, 48B, 16B-aligned)
template<int OUTF32>
__global__ __launch_bounds__(256) void gemm_bt(const unsigned short* __restrict__ A,
                                               const unsigned short* __restrict__ Bw,
                                               const float* __restrict__ bias,
                                               void* __restrict__ Cp,
                                               int M, int N, int K, int ldc){
  __shared__ __align__(16) unsigned short As[128 * 32];
  __shared__ __align__(16) unsigned short Bs[128 * 32];
  const int tid = threadIdx.x, lane = tid & 63, w = tid >> 6;
  const int col = lane & 15, q = lane >> 4;
  const int m0 = blockIdx.x * 128, n0 = blockIdx.y * 128;
  const int mW = (w & 1) * 64, nW = (w >> 1) * 64;
  const size_t rowb = (size_t)K * 2;

  f32x4 acc[4][4] = {};

  for (int k0 = 0; k0 < K; k0 += 32){
    __syncthreads();
    #pragma unroll
    for (int inst = 0; inst < 2; ++inst){
      int c = inst * 256 + w * 64 + lane;
      int row = c >> 2, c16 = c & 3;
      lds_load16((char*)As + (inst * 4096 + w * 1024),
                 (const char*)A  + (size_t)(m0 + row) * rowb + (size_t)k0 * 2 + c16 * 16);
      lds_load16((char*)Bs + (inst * 4096 + w * 1024),
                 (const char*)Bw + (size_t)(n0 + row) * rowb + (size_t)k0 * 2 + c16 * 16);
    }
    __syncthreads();
    s16x8 aF[4], bF[4];
    #pragma unroll
    for (int t = 0; t < 4; ++t){
      aF[t] = *(const s16x8*)&As[(mW + t * 16 + col) * 32 + q * 8];
      bF[t] = *(const s16x8*)&Bs[(nW + t * 16 + col) * 32 + q * 8];
    }
    #pragma unroll
    for (int mi = 0; mi < 4; ++mi)
      #pragma unroll
      for (int ni = 0; ni < 4; ++ni)
        acc[mi][ni] = __builtin_amdgcn_mfma_f32_16x16x32_bf16(aF[mi], bF[ni], acc[mi][ni], 0, 0, 0);
  }

  float bn[4];
  #pragma unroll
  for (int ni = 0; ni < 4; ++ni) bn[ni] = bias[n0 + nW + ni * 16 + col];

  if (OUTF32){
    #pragma unroll
    for (int mi = 0; mi < 4; ++mi)
      #pragma unroll
      for (int ni = 0; ni < 4; ++ni)
        #pragma unroll
        for (int i = 0; i < 4; ++i){
          int r  = m0 + mW + mi * 16 + 4 * q + i;
          int cN = n0 + nW + ni * 16 + col;
          ((float*)Cp)[(size_t)r * ldc + cN] = acc[mi][ni][i] + bn[ni];
        }
  } else {
    // rows m0..m0+127 all share one batch index b (2048 rows per b, m0 multiple of 128)
    const int b     = m0 >> 11;
    const int btile = b >> 4;
    const int qs16  = ((b & 15) >> 2) * 16;   // scan q*16
    const int isb   = b & 3;                  // scan i
    const int sbase = (m0 & 2047) + mW;
    #pragma unroll
    for (int mi = 0; mi < 4; ++mi)
      #pragma unroll
      for (int ni = 0; ni < 4; ++ni)
        #pragma unroll
        for (int i = 0; i < 4; ++i){
          int s  = sbase + mi * 16 + 4 * q + i;
          int cN = n0 + nW + ni * 16 + col;
          int g  = cN >> 8, d = cN & 255;
          int laneg = (d >> 5) * 64 + qs16 + (d & 15);
          int j  = (((d >> 4) & 1) * 4 + isb) * 3 + g;
          float v = acc[mi][ni][i] + bn[ni];
          ((unsigned short*)Cp)[((size_t)(btile * 2048 + s) * 512 + laneg) * 24 + j] = f2b(v);
        }
  }
}

// Recurrent scan for one layer. gi: scan-lane-major bf16 (see gemm_bt) ;
// Wh: [768][256] bf16 ; bh: [768] f32 ; out: [B][S][256] bf16.
// Grid = 4 (batch tiles of 16), block = 512 (8 waves).
// gi value j = (t2*4+i)*3+g lives in register chunk j>>3 element j&7.
#define GPICK(J) b2f((unsigned short)((J) < 8 ? v0[(J) & 7] : ((J) < 16 ? v1[(J) & 7] : v2[(J) & 7])))
__global__ __launch_bounds__(512, 2) void gru_scan(const unsigned short* __restrict__ gi,
                                                   const unsigned short* __restrict__ Wh,
                                                   const float* __restrict__ bh,
                                                   unsigned short* __restrict__ outp){
  __shared__ __align__(16) unsigned short hb[2][4096];   // 16 KB: h dbuf in A-frag order
  const int tid = threadIdx.x, lane = tid & 63, w = tid >> 6;
  const int col = lane & 15, q = lane >> 4;
  const int b0 = blockIdx.x * 16;
  const int dbase = w * 32;   // wave owns d in [dbase, dbase+32)

  // ---- Wh fragments in registers: bw[g*2+t2][kk], B-layout (n=lane&15, k=q*8+j)
  s16x8 bw[6][8];
  float bhv[6];
  #pragma unroll
  for (int g = 0; g < 3; ++g)
    #pragma unroll
    for (int t2 = 0; t2 < 2; ++t2){
      int gcol = g * 256 + dbase + t2 * 16 + col;
      bhv[g * 2 + t2] = bh[gcol];
      #pragma unroll
      for (int kk = 0; kk < 8; ++kk)
        bw[g * 2 + t2][kk] = *(const s16x8*)(Wh + gcol * 256 + kk * 32 + q * 8);
    }

  for (int i = tid; i < 4096; i += 512) hb[0][i] = 0;   // h0 = 0

  float hprev[2][4] = {};
  size_t obase[4];
  #pragma unroll
  for (int i = 0; i < 4; ++i)
    obase[i] = (size_t)(b0 + 4 * q + i) * (S_ * D_) + dbase + col;

  // gi: this lane's 48B chunk per step; step stride = 512*24 ushort = 1536 s16x8
  const s16x8* gp = (const s16x8*)(gi + ((size_t)blockIdx.x * (S_ * 512) + (size_t)(w * 64 + lane)) * 24);
  s16x8 gA0 = gp[0], gA1 = gp[1], gA2 = gp[2];   // s=0

  __syncthreads();

  auto step = [&](const unsigned short* hcur, unsigned short* hnxt,
                  s16x8 v0, s16x8 v1, s16x8 v2, int sidx){
    // gh = h @ Wh^T + bh  (acc init = bh)
    f32x4 acc[6];
    #pragma unroll
    for (int t = 0; t < 6; ++t){ f32x4 vv = {bhv[t], bhv[t], bhv[t], bhv[t]}; acc[t] = vv; }
    s16x8 a0 = *(const s16x8*)&hcur[lane * 8];
    #pragma unroll
    for (int kk = 0; kk < 8; ++kk){
      s16x8 aN = a0;
      if (kk < 7) aN = *(const s16x8*)&hcur[(kk + 1) * 512 + lane * 8];
      #pragma unroll
      for (int t = 0; t < 6; ++t)
        acc[t] = __builtin_amdgcn_mfma_f32_16x16x32_bf16(a0, bw[t][kk], acc[t], 0, 0, 0);
      a0 = aN;
    }
    // gates + h update, gi from registers
    #pragma unroll
    for (int t2 = 0; t2 < 2; ++t2){
      const int d = dbase + t2 * 16 + col;
      #pragma unroll
      for (int i = 0; i < 4; ++i){
        const int j0 = (t2 * 4 + i) * 3;
        float giR = GPICK(j0);
        float giZ = GPICK(j0 + 1);
        float giN = GPICK(j0 + 2);
        float pr = acc[t2][i]     + giR;
        float pz = acc[2 + t2][i] + giZ;
        float rg = __builtin_amdgcn_rcpf(1.f + __expf(-pr));
        float zg = __builtin_amdgcn_rcpf(1.f + __expf(-pz));
        float na = giN + rg * acc[4 + t2][i];
        float e2 = __expf(2.f * na);
        float ng = 1.f - 2.f * __builtin_amdgcn_rcpf(e2 + 1.f);   // tanh
        float hn = ng + zg * (hprev[t2][i] - ng);                 // (1-z)*n + z*h
        hprev[t2][i] = hn;
        unsigned short hbits = f2b(hn);
        outp[obase[i] + (size_t)sidx * D_ + t2 * 16] = hbits;
        // scatter into A-frag order for next step
        hnxt[(d >> 5) * 512 + ((4 * q + i) + 16 * ((d >> 3) & 3)) * 8 + (d & 7)] = hbits;
      }
    }
    // h exchange is the only cross-wave dependency: LDS-only barrier, no vmem drain.
    asm volatile("s_waitcnt lgkmcnt(0)" ::: "memory");
    __builtin_amdgcn_s_barrier();
    asm volatile("" ::: "memory");
  };

  s16x8 gB0, gB1, gB2;
  for (int s = 0; s < S_; s += 2){
    // prefetch s+1 ; clamp tail prefetch of s+2 to stay in-buffer (s is wave-uniform)
    gB0 = gp[1536]; gB1 = gp[1537]; gB2 = gp[1538];
    step(hb[0], hb[1], gA0, gA1, gA2, s);
    const s16x8* gpn = (s + 2 < S_) ? (gp + 3072) : gp;
    gA0 = gpn[0]; gA1 = gpn[1]; gA2 = gpn[2];              // prefetch s+2 (in-buffer always)
    step(hb[1], hb[0], gB0, gB1, gB2, s + 1);
    gp += 3072;
  }
}

extern "C" void kernel_launch(void* const* d_in, const int* in_sizes, int n_in,
                              void* d_out, int out_size, void* d_ws, size_t ws_size,
                              hipStream_t stream){
  const int*   x    = (const int*)  d_in[0];
  const float* emb  = (const float*)d_in[1];
  const float* Wih  = (const float*)d_in[2];
  const float* Whh  = (const float*)d_in[3];
  const float* bih  = (const float*)d_in[4];
  const float* bhh  = (const float*)d_in[5];
  const float* Wout = (const float*)d_in[6];
  const float* bout = (const float*)d_in[7];
  float* out = (float*)d_out;

  char* ws = (char*)d_ws;
  unsigned short* seqA  = (unsigned short*)(ws);                 //  67,108,864 B
  unsigned short* seqB  = (unsigned short*)(ws +  67108864);     //  67,108,864 B
  unsigned short* gibuf = (unsigned short*)(ws + 134217728);     // 201,326,592 B scan-lane-major
  unsigned short* wihB  = (unsigned short*)(ws + 335544320);     //   1,572,864 B
  unsigned short* whhB  = (unsigned short*)(ws + 337117184);     //   1,572,864 B
  unsigned short* woutB = (unsigned short*)(ws + 338690048);     //     131,072 B

  cast_bf16_kernel<<<3072, 256, 0, stream>>>(Wih,  wihB,  L_ * 768 * 256);
  cast_bf16_kernel<<<3072, 256, 0, stream>>>(Whh,  whhB,  L_ * 768 * 256);
  cast_bf16_kernel<<< 256, 256, 0, stream>>>(Wout, woutB, V_ * D_);
  embed_kernel<<<B_ * S_, 256, 0, stream>>>(x, emb, seqA);

  const int M = B_ * S_;   // 131072
  unsigned short* sIn = seqA;
  unsigned short* sOut = seqB;
  for (int l = 0; l < L_; ++l){
    gemm_bt<0><<<dim3(M / 128, 6), 256, 0, stream>>>(sIn, wihB + (size_t)l * 768 * 256,
                                                     bih + l * 768, gibuf, M, 768, 256, 768);
    gru_scan<<<4, 512, 0, stream>>>(gibuf, whhB + (size_t)l * 768 * 256, bhh + l * 768, sOut);
    unsigned short* t = sIn; sIn = sOut; sOut = t;
  }
  gemm_bt<1><<<dim3(M / 128, 2), 256, 0, stream>>>(sIn, woutB, bout, out, M, 256, 256, 256);
}

// Round 3
// 8921.959 us; speedup vs baseline: 3.2473x; 2.6829x over previous
//
#include <hip/hip_runtime.h>
#include <hip/hip_bf16.h>

// GRU backbone: B=64 S=2048 D=256 V=256 L=4
// Phases per call: cast weights->bf16, embed, then per layer {gi GEMM, scan}, final GEMM.
// Scan NEW this round: 16 blocks x batch-tile 4 (16 CUs, was 4). A-operand carries the
// 4 batch rows replicated (A row m = h[m/4]); MFMA C layout row=4q+i then gives every
// lane a distinct valid element at acc[t][0] -> gate VALU per lane drops 8 els -> 2 els.
// Only A rows 4q are consumed, so only those are written (2 ds_write_b16/lane/step).
// gi is dword-packed per scan-lane (3 coalesced dword loads/step, reg double-buffered).
// Per-step sync stays lgkmcnt(0)-only raw s_barrier (no vmem drain).

#define B_ 64
#define S_ 2048
#define D_ 256
#define V_ 256
#define L_ 4

typedef short  s16x8 __attribute__((ext_vector_type(8)));
typedef float  f32x4 __attribute__((ext_vector_type(4)));

static __device__ __forceinline__ unsigned short f2b(float f){
  union { float f; unsigned int u; } v; v.f = f;
  unsigned int u = v.u;
  return (unsigned short)((u + 0x7FFFu + ((u >> 16) & 1u)) >> 16);  // RNE
}
static __device__ __forceinline__ float b2f_lo(unsigned int u){
  union { unsigned int u; float f; } v; v.u = u << 16; return v.f;
}
static __device__ __forceinline__ float b2f_hi(unsigned int u){
  union { unsigned int u; float f; } v; v.u = u & 0xffff0000u; return v.f;
}

static __device__ __forceinline__ void lds_load16(void* lds, const void* g){
  __builtin_amdgcn_global_load_lds(
      (const __attribute__((address_space(1))) unsigned int*)g,
      (__attribute__((address_space(3))) unsigned int*)lds, 16, 0, 0);
}

__global__ void cast_bf16_kernel(const float* __restrict__ src,
                                 unsigned short* __restrict__ dst, int n){
  int i = blockIdx.x * 256 + threadIdx.x;
  if (i < n) dst[i] = f2b(src[i]);
}

__global__ void embed_kernel(const int* __restrict__ x, const float* __restrict__ emb,
                             unsigned short* __restrict__ seq){
  int bs = blockIdx.x;
  int d  = threadIdx.x;
  int tok = x[bs];
  seq[(size_t)bs * D_ + d] = f2b(emb[tok * D_ + d]);
}

// C[M,N] = A[M,K] * Bw[N,K]^T + bias ; A,Bw bf16 ; 128x128 tile, BK=32
// OUTF32=1: f32 row-major output (final logits GEMM).
// OUTF32=0: bf16 output, dword-packed scan-lane-major for gru_scan (16 blocks x batch 4):
//   element (b, s, gate g, hidden d):
//     bi = b>>2 (scan block), qs = b&3 (scan q), lane_s = (d>>5)*64 + qs*16 + (d&15)
//     j = ((d>>4)&1)*3 + g  in [0,6)  -> dword jp = j>>1, half j&1
//     ushort addr = (((bi*2048+s)*3 + jp)*512 + lane_s)*2 + (j&1)
//   i.e. per (block,step): 3 dword-planes of 512 lanes; scan lane reads gp[0],gp[512],gp[1024].
template<int OUTF32>
__global__ __launch_bounds__(256) void gemm_bt(const unsigned short* __restrict__ A,
                                               const unsigned short* __restrict__ Bw,
                                               const float* __restrict__ bias,
                                               void* __restrict__ Cp,
                                               int M, int N, int K, int ldc){
  __shared__ __align__(16) unsigned short As[128 * 32];
  __shared__ __align__(16) unsigned short Bs[128 * 32];
  const int tid = threadIdx.x, lane = tid & 63, w = tid >> 6;
  const int col = lane & 15, q = lane >> 4;
  const int m0 = blockIdx.x * 128, n0 = blockIdx.y * 128;
  const int mW = (w & 1) * 64, nW = (w >> 1) * 64;
  const size_t rowb = (size_t)K * 2;

  f32x4 acc[4][4] = {};

  for (int k0 = 0; k0 < K; k0 += 32){
    __syncthreads();
    #pragma unroll
    for (int inst = 0; inst < 2; ++inst){
      int c = inst * 256 + w * 64 + lane;
      int row = c >> 2, c16 = c & 3;
      lds_load16((char*)As + (inst * 4096 + w * 1024),
                 (const char*)A  + (size_t)(m0 + row) * rowb + (size_t)k0 * 2 + c16 * 16);
      lds_load16((char*)Bs + (inst * 4096 + w * 1024),
                 (const char*)Bw + (size_t)(n0 + row) * rowb + (size_t)k0 * 2 + c16 * 16);
    }
    __syncthreads();
    s16x8 aF[4], bF[4];
    #pragma unroll
    for (int t = 0; t < 4; ++t){
      aF[t] = *(const s16x8*)&As[(mW + t * 16 + col) * 32 + q * 8];
      bF[t] = *(const s16x8*)&Bs[(nW + t * 16 + col) * 32 + q * 8];
    }
    #pragma unroll
    for (int mi = 0; mi < 4; ++mi)
      #pragma unroll
      for (int ni = 0; ni < 4; ++ni)
        acc[mi][ni] = __builtin_amdgcn_mfma_f32_16x16x32_bf16(aF[mi], bF[ni], acc[mi][ni], 0, 0, 0);
  }

  float bn[4];
  #pragma unroll
  for (int ni = 0; ni < 4; ++ni) bn[ni] = bias[n0 + nW + ni * 16 + col];

  if (OUTF32){
    #pragma unroll
    for (int mi = 0; mi < 4; ++mi)
      #pragma unroll
      for (int ni = 0; ni < 4; ++ni)
        #pragma unroll
        for (int i = 0; i < 4; ++i){
          int r  = m0 + mW + mi * 16 + 4 * q + i;
          int cN = n0 + nW + ni * 16 + col;
          ((float*)Cp)[(size_t)r * ldc + cN] = acc[mi][ni][i] + bn[ni];
        }
  } else {
    // rows m0..m0+127 all share one batch index b (2048 rows per b, m0 multiple of 128)
    const int b     = m0 >> 11;
    const int bi    = b >> 2;
    const int qs    = b & 3;
    const int sbase = (m0 & 2047) + mW;
    #pragma unroll
    for (int mi = 0; mi < 4; ++mi)
      #pragma unroll
      for (int ni = 0; ni < 4; ++ni)
        #pragma unroll
        for (int i = 0; i < 4; ++i){
          int s  = sbase + mi * 16 + 4 * q + i;
          int cN = n0 + nW + ni * 16 + col;
          int g  = cN >> 8, d = cN & 255;
          int lane_s = (d >> 5) * 64 + qs * 16 + (d & 15);
          int j  = ((d >> 4) & 1) * 3 + g;
          float v = acc[mi][ni][i] + bn[ni];
          size_t us = ((size_t)((bi * 2048 + s) * 3 + (j >> 1)) * 512 + lane_s) * 2 + (j & 1);
          ((unsigned short*)Cp)[us] = f2b(v);
        }
  }
}

// Recurrent scan for one layer. gi32: dword-packed scan-lane-major (see gemm_bt) ;
// Wh: [768][256] bf16 ; bh: [768] f32 ; out: [B][S][256] bf16.
// Grid = 16 (batch tiles of 4), block = 512 (8 waves).
// A-frag rows: row m holds h[batch m/4]; only rows 4q are written (others stay 0).
// Lane (q,col) consumes acc[t][0] = gh(batch q, d = w*32 + t2*16 + col).
__global__ __launch_bounds__(512, 2) void gru_scan(const unsigned int* __restrict__ gi32,
                                                   const unsigned short* __restrict__ Wh,
                                                   const float* __restrict__ bh,
                                                   unsigned short* __restrict__ outp){
  __shared__ __align__(16) unsigned short hb[2][4096];   // 16 KB: h dbuf in A-frag order
  const int tid = threadIdx.x, lane = tid & 63, w = tid >> 6;
  const int col = lane & 15, q = lane >> 4;
  const int bi = blockIdx.x;
  const int dbase = w * 32;   // wave owns d in [dbase, dbase+32)

  // ---- Wh fragments in registers: bw[g*2+t2][kk], B-layout (n=lane&15, k=q*8+j)
  s16x8 bw[6][8];
  float bhv[6];
  #pragma unroll
  for (int g = 0; g < 3; ++g)
    #pragma unroll
    for (int t2 = 0; t2 < 2; ++t2){
      int gcol = g * 256 + dbase + t2 * 16 + col;
      bhv[g * 2 + t2] = bh[gcol];
      #pragma unroll
      for (int kk = 0; kk < 8; ++kk)
        bw[g * 2 + t2][kk] = *(const s16x8*)(Wh + gcol * 256 + kk * 32 + q * 8);
    }

  for (int i = tid; i < 4096; i += 512){ hb[0][i] = 0; hb[1][i] = 0; }  // rows 4q+1..3 stay 0 forever

  float hprev[2] = {0.f, 0.f};
  const size_t obase = (size_t)(bi * 4 + q) * (S_ * D_) + dbase + col;

  // gi: 3 dword-planes per (block,step); lane reads gp[0], gp[512], gp[1024]; step stride 1536
  const unsigned int* gp = gi32 + (size_t)bi * (S_ * 1536) + (w * 64 + lane);
  unsigned int cA0 = gp[0], cA1 = gp[512], cA2 = gp[1024];   // s=0

  __syncthreads();

  auto step = [&](const unsigned short* hcur, unsigned short* hnxt,
                  unsigned int c0, unsigned int c1, unsigned int c2, int sidx){
    // gh = h @ Wh^T + bh  (acc init = bh)
    f32x4 acc[6];
    #pragma unroll
    for (int t = 0; t < 6; ++t){ f32x4 vv = {bhv[t], bhv[t], bhv[t], bhv[t]}; acc[t] = vv; }
    s16x8 a0 = *(const s16x8*)&hcur[lane * 8];
    #pragma unroll
    for (int kk = 0; kk < 8; ++kk){
      s16x8 aN = a0;
      if (kk < 7) aN = *(const s16x8*)&hcur[(kk + 1) * 512 + lane * 8];
      #pragma unroll
      for (int t = 0; t < 6; ++t)
        acc[t] = __builtin_amdgcn_mfma_f32_16x16x32_bf16(a0, bw[t][kk], acc[t], 0, 0, 0);
      a0 = aN;
    }
    // gates + h update: 2 elements per lane (batch q, d = dbase + t2*16 + col)
    // j = t2*3+g packing: c0 = (r0,z0), c1 = (n0,r1), c2 = (z1,n1)
    float giR[2] = { b2f_lo(c0), b2f_hi(c1) };
    float giZ[2] = { b2f_hi(c0), b2f_lo(c2) };
    float giN[2] = { b2f_lo(c1), b2f_hi(c2) };
    #pragma unroll
    for (int t2 = 0; t2 < 2; ++t2){
      const int d = dbase + t2 * 16 + col;
      float pr = acc[t2][0]     + giR[t2];
      float pz = acc[2 + t2][0] + giZ[t2];
      float rg = __builtin_amdgcn_rcpf(1.f + __expf(-pr));
      float zg = __builtin_amdgcn_rcpf(1.f + __expf(-pz));
      float na = giN[t2] + rg * acc[4 + t2][0];
      float e2 = __expf(2.f * na);
      float ng = 1.f - 2.f * __builtin_amdgcn_rcpf(e2 + 1.f);   // tanh
      float hn = ng + zg * (hprev[t2] - ng);                    // (1-z)*n + z*h
      hprev[t2] = hn;
      unsigned short hbits = f2b(hn);
      outp[obase + (size_t)sidx * D_ + t2 * 16] = hbits;
      // A-frag scatter, row m = 4q only (rows 4q+1..3 remain zero, never consumed)
      hnxt[(d >> 5) * 512 + ((4 * q) + 16 * ((d >> 3) & 3)) * 8 + (d & 7)] = hbits;
    }
    // h exchange is the only cross-wave dependency: LDS-only barrier, no vmem drain.
    asm volatile("s_waitcnt lgkmcnt(0)" ::: "memory");
    __builtin_amdgcn_s_barrier();
    asm volatile("" ::: "memory");
  };

  unsigned int cB0, cB1, cB2;
  for (int s = 0; s < S_; s += 2){
    cB0 = gp[1536]; cB1 = gp[1536 + 512]; cB2 = gp[1536 + 1024];   // prefetch s+1
    step(hb[0], hb[1], cA0, cA1, cA2, s);
    const unsigned int* gpn = (s + 2 < S_) ? (gp + 3072) : gp;     // clamped tail prefetch
    cA0 = gpn[0]; cA1 = gpn[512]; cA2 = gpn[1024];                 // prefetch s+2
    step(hb[1], hb[0], cB0, cB1, cB2, s + 1);
    gp += 3072;
  }
}

extern "C" void kernel_launch(void* const* d_in, const int* in_sizes, int n_in,
                              void* d_out, int out_size, void* d_ws, size_t ws_size,
                              hipStream_t stream){
  const int*   x    = (const int*)  d_in[0];
  const float* emb  = (const float*)d_in[1];
  const float* Wih  = (const float*)d_in[2];
  const float* Whh  = (const float*)d_in[3];
  const float* bih  = (const float*)d_in[4];
  const float* bhh  = (const float*)d_in[5];
  const float* Wout = (const float*)d_in[6];
  const float* bout = (const float*)d_in[7];
  float* out = (float*)d_out;

  char* ws = (char*)d_ws;
  unsigned short* seqA  = (unsigned short*)(ws);                 //  67,108,864 B
  unsigned short* seqB  = (unsigned short*)(ws +  67108864);     //  67,108,864 B
  unsigned short* gibuf = (unsigned short*)(ws + 134217728);     // 201,326,592 B dword-packed scan-lane-major
  unsigned short* wihB  = (unsigned short*)(ws + 335544320);     //   1,572,864 B
  unsigned short* whhB  = (unsigned short*)(ws + 337117184);     //   1,572,864 B
  unsigned short* woutB = (unsigned short*)(ws + 338690048);     //     131,072 B

  cast_bf16_kernel<<<3072, 256, 0, stream>>>(Wih,  wihB,  L_ * 768 * 256);
  cast_bf16_kernel<<<3072, 256, 0, stream>>>(Whh,  whhB,  L_ * 768 * 256);
  cast_bf16_kernel<<< 256, 256, 0, stream>>>(Wout, woutB, V_ * D_);
  embed_kernel<<<B_ * S_, 256, 0, stream>>>(x, emb, seqA);

  const int M = B_ * S_;   // 131072
  unsigned short* sIn = seqA;
  unsigned short* sOut = seqB;
  for (int l = 0; l < L_; ++l){
    gemm_bt<0><<<dim3(M / 128, 6), 256, 0, stream>>>(sIn, wihB + (size_t)l * 768 * 256,
                                                     bih + l * 768, gibuf, M, 768, 256, 768);
    gru_scan<<<16, 512, 0, stream>>>((const unsigned int*)gibuf,
                                     whhB + (size_t)l * 768 * 256, bhh + l * 768, sOut);
    unsigned short* t = sIn; sIn = sOut; sOut = t;
  }
  gemm_bt<1><<<dim3(M / 128, 2), 256, 0, stream>>>(sIn, woutB, bout, out, M, 256, 256, 256);
}